// Round 9
// baseline (202.586 us; speedup 1.0000x reference)
//
#include <hip/hip_runtime.h>
#include <hip/hip_bf16.h>

#define NB 8
#define NC 128
#define NT 4096
#define NS 1024

typedef short bf16x8 __attribute__((ext_vector_type(8)));
typedef float f32x4  __attribute__((ext_vector_type(4)));
typedef float f32x16 __attribute__((ext_vector_type(16)));

#define MFMA16(a, b, c) __builtin_amdgcn_mfma_f32_16x16x32_bf16(a, b, c, 0, 0, 0)
#define MFMA32(a, b, c) __builtin_amdgcn_mfma_f32_32x32x16_bf16(a, b, c, 0, 0, 0)

__device__ __forceinline__ short f2b(float x) {
    __hip_bfloat16 h = __float2bfloat16(x);
    return *reinterpret_cast<short*>(&h);
}

__device__ __forceinline__ unsigned pk2(float a, float b) {
    return (unsigned)(unsigned short)f2b(a) | ((unsigned)(unsigned short)f2b(b) << 16);
}

// async global->LDS, 16B per lane; dest = wave-uniform base + lane*16 (linear)
__device__ __forceinline__ void gl_lds16(const void* g, void* l) {
    __builtin_amdgcn_global_load_lds(
        (const __attribute__((address_space(1))) unsigned int*)g,
        (__attribute__((address_space(3))) unsigned int*)l, 16, 0, 0);
}

// ---------------------------------------------------------------------------
// Doubled-K packed-weight B-fragment built DIRECTLY from the f32 weight pair
// (replaces the pack_w kernel).  Packed row `col` of the [256][256] matrix:
//   col<128 (real out):  k<128 -> Wr[col][k],  k>=128 -> -Wi[col][k-128]
//   col>=128 (imag out): k<128 -> Wi[c][k],    k>=128 ->  Wr[c][k-128]
// k-window [k0, k0+8) never straddles k=128 (k0 = t*32 + q*8).
// For V (rows are real-out only, col<128) the first branch applies.
// ---------------------------------------------------------------------------
__device__ __forceinline__ bf16x8 wfrag(const float* __restrict__ Wr,
                                        const float* __restrict__ Wi,
                                        int col, int k0)
{
    const int c = col & 127, kk = k0 & 127;
    const float* src;
    float sgn = 1.f;
    if (col < 128) {
        if (k0 < 128) src = Wr + c * 128 + kk;
        else        { src = Wi + c * 128 + kk; sgn = -1.f; }
    } else {
        src = ((k0 < 128) ? Wi : Wr) + c * 128 + kk;
    }
    const f32x4 a = *(const f32x4*)src;
    const f32x4 d = *(const f32x4*)(src + 4);
    bf16x8 f;
    f[0] = f2b(a[0] * sgn); f[1] = f2b(a[1] * sgn);
    f[2] = f2b(a[2] * sgn); f[3] = f2b(a[3] * sgn);
    f[4] = f2b(d[0] * sgn); f[5] = f2b(d[1] * sgn);
    f[6] = f2b(d[2] * sgn); f[7] = f2b(d[3] * sgn);
    return f;
}

// ---------------------------------------------------------------------------
// Merged K + V projection, weights read directly as f32 (no pack kernel).
// 16-source-row tiles -> 512 blocks (2 blocks/CU).
// ---------------------------------------------------------------------------
__global__ __launch_bounds__(256) void projKV_kernel(
    const float* __restrict__ Xr, const float* __restrict__ Xi,
    const float* __restrict__ Wkr, const float* __restrict__ Wki,
    const float* __restrict__ bkr, const float* __restrict__ bki,
    const float* __restrict__ Wvr, const float* __restrict__ Wvi,
    const float* __restrict__ bvr,
    __hip_bfloat16* __restrict__ Kh, __hip_bfloat16* __restrict__ VrT)
{
    __shared__ __align__(16) char smem[13568];   // As[16][528] + Vstash[128][40]
    const int b   = blockIdx.x & 7;              // batch -> XCD affinity
    const int n0  = (blockIdx.x >> 3) * 16;
    const int tid = threadIdx.x;

    for (int i = tid; i < 16 * 64; i += 256) {
        const int cp = i >> 4, n = i & 15, c = cp * 2;
        const size_t rb = (size_t)(b * NC + c) * NS + n0 + n;
        *(unsigned*)(smem + n * 528 + c * 2)         = pk2(Xr[rb], Xr[rb + NS]);
        *(unsigned*)(smem + n * 528 + (128 + c) * 2) = pk2(Xi[rb], Xi[rb + NS]);
    }
    __syncthreads();

    const int w = tid >> 6, l15 = tid & 15, q8 = (tid & 63) >> 4;

    f32x4 acc[6];
    #pragma unroll
    for (int jj = 0; jj < 6; ++jj) { acc[jj][0]=0.f; acc[jj][1]=0.f; acc[jj][2]=0.f; acc[jj][3]=0.f; }

    #pragma unroll
    for (int t = 0; t < 8; ++t) {
        const bf16x8 af = *(const bf16x8*)(smem + l15 * 528 + (t * 32 + q8 * 8) * 2);
        const int k0 = t * 32 + q8 * 8;
        #pragma unroll
        for (int jj = 0; jj < 6; ++jj) {
            const int j = w * 6 + jj;            // global col tile 0..23
            const bf16x8 bf = (j < 16)
                ? wfrag(Wkr, Wki, j * 16 + l15, k0)
                : wfrag(Wvr, Wvi, (j - 16) * 16 + l15, k0);
            acc[jj] = MFMA16(af, bf, acc[jj]);
        }
    }

    #pragma unroll
    for (int jj = 0; jj < 6; ++jj) {
        const int j = w * 6 + jj;
        if (j < 16) {                            // K epilogue: direct global
            const int col = j * 16 + l15;
            const float bv = (col < 128) ? bkr[col] : bki[col - 128];
            #pragma unroll
            for (int r = 0; r < 4; ++r) {
                const int n = n0 + q8 * 4 + r;
                Kh[((size_t)(b * NS + n) << 8) + col] = __float2bfloat16(acc[jj][r] + bv);
            }
        } else {                                 // V epilogue: LDS transpose stash
            const int d = (j - 16) * 16 + l15;
            #pragma unroll
            for (int r = 0; r < 4; ++r)
                *(__hip_bfloat16*)(smem + 8448 + d * 40 + (q8 * 4 + r) * 2) =
                    __float2bfloat16(acc[jj][r] + bvr[d]);
        }
    }
    __syncthreads();
    for (int i = tid; i < 128 * 2; i += 256) {
        const int d = i >> 1, seg = i & 1;
        const int4 v = *(const int4*)(smem + 8448 + d * 40 + seg * 16);
        *(int4*)((char*)VrT + ((size_t)(b * NC + d) * NS + n0) * 2 + seg * 16) = v;
    }
}

// ---------------------------------------------------------------------------
// Stage one 32-source-row chunk into LDS buffer `buf`, TRANSPOSED layouts:
//   K region  [0,16384):  addr = slot*512  + row*16   (32 slots x 32 rows)
//   V region  [16384,24K): addr = slot*2048 + d*16    (4 slots x 128 d-rows)
// All in-loop fragment reads are then lane-sequential (base + lane*16):
// structurally conflict-free, no swizzle math.  global_load_lds dest is
// linear (base + lane*16); the per-lane GLOBAL source provides the transpose.
// ---------------------------------------------------------------------------
__device__ __forceinline__ void stage_chunk(const char* Kbase, const char* Vbase,
                                            char* buf, int ch, int w, int lane)
{
    const char* ks = Kbase + (size_t)ch * 16384;
    #pragma unroll
    for (int i = 0; i < 4; ++i) {
        const int j    = w * 4 + i;                 // instr 0..15 (2 slots each)
        const int slot = 2 * j + (lane >> 5);
        const int row  = lane & 31;
        gl_lds16(ks + row * 512 + slot * 16, buf + j * 1024);
    }
    const char* vs = Vbase + (size_t)ch * 64;
    #pragma unroll
    for (int i = 0; i < 2; ++i) {
        const int idx  = w * 2 + i;                 // instr 0..7
        const int slot = idx >> 1;
        const int d    = (idx & 1) * 64 + lane;
        gl_lds16(vs + (size_t)d * 2048 + slot * 16, buf + 16384 + idx * 1024);
    }
}

// ---------------------------------------------------------------------------
// Flash attention, 32x32 MFMA.  Block = batch b x 64 target rows.
// Waves 0,1 own q-halves on EVEN chunks; waves 2,3 on ODD (all co-stage).
// Swapped QK^T (mfma32(K,Q)): S lane-local; PV A-frag assembled in-register
// via pack + shfl_xor(32).  No-max softmax (p = 2^S', scale folded into
// Q-hat); denominator via all-ones-B MFMA.  Cooperative Q-proj reads Wq
// DIRECTLY as f32 (packing folded into wfrag).  Transposed, conflict-free
// K/V chunk layouts; triple-buffered, counted vmcnt(6) + raw s_barrier.
// ---------------------------------------------------------------------------
__global__ __launch_bounds__(256, 2) void attn_mfma_kernel(
    const float* __restrict__ tr_g, const float* __restrict__ ti_g,
    const float* __restrict__ Wqr, const float* __restrict__ Wqi,
    const float* __restrict__ bqr, const float* __restrict__ bqi,
    const __hip_bfloat16* __restrict__ Kh, const __hip_bfloat16* __restrict__ VrT,
    const float* __restrict__ gamma_p, float* __restrict__ out)
{
    __shared__ __align__(16) char smem[73728];
    // Phase A: As[64][528] @0, Qh[64][528] @33792.
    // Phase B: 3 x 24576 chunk buffers @0.
    // Phase C: Of0[128][65]f32 @0, Of1 @33280, l[2][64] @66560, invl @67072.
    char* As = smem;
    char* Qh = smem + 33792;

    const int bid = blockIdx.x, tid = threadIdx.x;
    const int b   = bid & 7;                     // batch -> XCD affinity
    const int n0  = (bid >> 3) * 64;
    const int w   = tid >> 6, lane = tid & 63;
    const int l15 = lane & 15, q8 = lane >> 4;   // 16x16 geometry
    const int l31 = lane & 31, hi = lane >> 5;   // 32x32 geometry
    const int w01 = w & 1, wprt = w >> 1;        // q-half, chunk parity

    // ---- stage target tile As[n][c] (64 x 256 bf16) ----
    for (int i = tid; i < 64 * 64; i += 256) {
        const int cp = i >> 6, n = i & 63, c = cp * 2;
        const size_t rb = (size_t)(b * NC + c) * NT + n0 + n;
        *(unsigned*)(As + n * 528 + c * 2)         = pk2(tr_g[rb], tr_g[rb + NT]);
        *(unsigned*)(As + n * 528 + (128 + c) * 2) = pk2(ti_g[rb], ti_g[rb + NT]);
    }
    __syncthreads();

    // ---- cooperative Q-proj: wave w -> cols 64w..64w+63, all 64 rows ----
    {
        f32x4 qacc[4][4];
        #pragma unroll
        for (int rg = 0; rg < 4; ++rg)
            #pragma unroll
            for (int jj = 0; jj < 4; ++jj) {
                qacc[rg][jj][0]=0.f; qacc[rg][jj][1]=0.f;
                qacc[rg][jj][2]=0.f; qacc[rg][jj][3]=0.f;
            }
        #pragma unroll
        for (int t = 0; t < 8; ++t) {
            bf16x8 af[4];
            #pragma unroll
            for (int rg = 0; rg < 4; ++rg)
                af[rg] = *(const bf16x8*)(As + (rg * 16 + l15) * 528 + (t * 32 + q8 * 8) * 2);
            const int k0 = t * 32 + q8 * 8;
            #pragma unroll
            for (int jj = 0; jj < 4; ++jj) {
                const bf16x8 bf = wfrag(Wqr, Wqi, (w * 4 + jj) * 16 + l15, k0);
                #pragma unroll
                for (int rg = 0; rg < 4; ++rg)
                    qacc[rg][jj] = MFMA16(af[rg], bf, qacc[rg][jj]);
            }
        }
        const float inv_s = 0.12751744f;          // log2(e) / sqrt(128)
        #pragma unroll
        for (int jj = 0; jj < 4; ++jj) {
            const int col  = (w * 4 + jj) * 16 + l15;
            const float bv = (col < 128) ? bqr[col] : bqi[col - 128];
            #pragma unroll
            for (int rg = 0; rg < 4; ++rg)
                #pragma unroll
                for (int r = 0; r < 4; ++r)
                    *(__hip_bfloat16*)(Qh + (rg * 16 + q8 * 4 + r) * 528 + col * 2) =
                        __float2bfloat16((qacc[rg][jj][r] + bv) * inv_s);
        }
    }
    __syncthreads();

    // ---- extract qf[16]: B-frags of my 32 q-rows ----
    bf16x8 qf[16];
    #pragma unroll
    for (int t = 0; t < 16; ++t)
        qf[t] = *(const bf16x8*)(Qh + (w01 * 32 + l31) * 528 + t * 32 + hi * 16);
    __syncthreads();        // Qh/As dead; buffer region free

    const char* Kbase = (const char*)Kh + ((size_t)(b * NS) << 9);
    const char* Vbase = (const char*)VrT + (size_t)b * NC * NS * 2;
    char* bA = smem;
    char* bB = smem + 24576;
    char* bC = smem + 49152;

    stage_chunk(Kbase, Vbase, bA, 0, w, lane);
    stage_chunk(Kbase, Vbase, bB, 1, w, lane);

    f32x16 oacc[4];
    #pragma unroll
    for (int jd = 0; jd < 4; ++jd)
        #pragma unroll
        for (int r = 0; r < 16; ++r) oacc[jd][r] = 0.f;
    f32x16 lacc;
    #pragma unroll
    for (int r = 0; r < 16; ++r) lacc[r] = 0.f;

    bf16x8 onesf;                    // all-ones B: D[q][*] = row sums of P
    #pragma unroll
    for (int e = 0; e < 8; ++e) onesf[e] = (short)0x3F80;

    #pragma unroll 1
    for (int ch = 0; ch < 32; ++ch) {
        asm volatile("s_waitcnt vmcnt(6)" ::: "memory");
        __builtin_amdgcn_s_barrier();    // raw: no vmcnt(0) drain

        const int sch = (ch + 2 < 32) ? ch + 2 : 31;
        stage_chunk(Kbase, Vbase, bC, sch, w, lane);

        if ((ch & 1) == wprt) {
            // ---- QK^T: S = mfma32(K, Q); conflict-free lane-seq reads ----
            f32x16 s;
            #pragma unroll
            for (int r = 0; r < 16; ++r) s[r] = 0.f;
            #pragma unroll
            for (int t = 0; t < 16; ++t) {
                const bf16x8 kf = *(const bf16x8*)(bA + ((2 * t + hi) << 9) + (l31 << 4));
                s = MFMA32(kf, qf[t], s);
            }
            // ---- p = 2^S' ----
            #pragma unroll
            for (int r = 0; r < 16; ++r) s[r] = exp2f(s[r]);

            // ---- assemble PV A-frags per 16-k window; PV + denominator ----
            #pragma unroll
            for (int t2 = 0; t2 < 2; ++t2) {
                const int o = t2 * 8;
                const unsigned x0 = pk2(s[o + 0], s[o + 1]);
                const unsigned x1 = pk2(s[o + 2], s[o + 3]);
                const unsigned y0 = pk2(s[o + 4], s[o + 5]);
                const unsigned y1 = pk2(s[o + 6], s[o + 7]);
                const unsigned xs0 = __shfl_xor(x0, 32);
                const unsigned xs1 = __shfl_xor(x1, 32);
                const unsigned ys0 = __shfl_xor(y0, 32);
                const unsigned ys1 = __shfl_xor(y1, 32);
                union { unsigned u[4]; bf16x8 v; } pu;
                pu.u[0] = hi ? ys0 : x0;
                pu.u[1] = hi ? ys1 : x1;
                pu.u[2] = hi ? y0  : xs0;
                pu.u[3] = hi ? y1  : xs1;
                const bf16x8 paf = pu.v;
                lacc = MFMA32(paf, onesf, lacc);
                #pragma unroll
                for (int jd = 0; jd < 4; ++jd) {
                    const bf16x8 vf = *(const bf16x8*)(
                        bA + 16384 + ((2 * t2 + hi) << 11) + ((jd * 32 + l31) << 4));
                    oacc[jd] = MFMA32(paf, vf, oacc[jd]);
                }
            }
        }

        char* t0 = bA; bA = bB; bB = bC; bC = t0;   // rotate buffers
    }

    // ---- epilogue: merge parity partials through LDS ----
    __syncthreads();                         // drains staging; buffers dead
    float* Ofp = (float*)(smem + wprt * 33280);   // my parity's partial
    #pragma unroll
    for (int jd = 0; jd < 4; ++jd)
        #pragma unroll
        for (int r = 0; r < 16; ++r) {
            const int m = w01 * 32 + (r & 3) + 8 * (r >> 2) + 4 * hi;
            Ofp[(jd * 32 + l31) * 65 + m] = oacc[jd][r];
        }
    float* lf = (float*)(smem + 66560);
    if (l31 == 0) {
        #pragma unroll
        for (int r = 0; r < 16; ++r) {
            const int m = w01 * 32 + (r & 3) + 8 * (r >> 2) + 4 * hi;
            lf[wprt * 64 + m] = lacc[r];
        }
    }
    __syncthreads();
    float* invl = (float*)(smem + 67072);
    if (tid < 64)
        invl[tid] = gamma_p[0] / fmaxf(lf[tid] + lf[64 + tid], 1e-30f);
    __syncthreads();

    const float* Of0 = (const float*)smem;
    const float* Of1 = (const float*)(smem + 33280);
    float* ob = out + (size_t)b * NC * NT + n0;
    for (int i = tid; i < 128 * 64; i += 256) {
        const int d = i >> 6, m = i & 63;
        ob[(size_t)d * NT + m] = (Of0[d * 65 + m] + Of1[d * 65 + m]) * invl[m];
    }
}

// ---------------------------------------------------------------------------
extern "C" void kernel_launch(void* const* d_in, const int* in_sizes, int n_in,
                              void* d_out, int out_size, void* d_ws, size_t ws_size,
                              hipStream_t stream)
{
    const float* target_r = (const float*)d_in[0];
    const float* target_i = (const float*)d_in[1];
    const float* source_r = (const float*)d_in[2];
    const float* source_i = (const float*)d_in[3];
    const float* Wq_r = (const float*)d_in[4];
    const float* Wq_i = (const float*)d_in[5];
    const float* bq_r = (const float*)d_in[6];
    const float* bq_i = (const float*)d_in[7];
    const float* Wk_r = (const float*)d_in[8];
    const float* Wk_i = (const float*)d_in[9];
    const float* bk_r = (const float*)d_in[10];
    const float* bk_i = (const float*)d_in[11];
    const float* Wv_r = (const float*)d_in[12];
    const float* Wv_i = (const float*)d_in[13];
    const float* bv_r = (const float*)d_in[14];
    const float* gamma = (const float*)d_in[16];

    // workspace carve (bytes) — total 6.29 MB
    char* ws = (char*)d_ws;
    __hip_bfloat16* Kh  = (__hip_bfloat16*)(ws);                    // 4,194,304
    __hip_bfloat16* VrT = (__hip_bfloat16*)(ws + 4194304);          // 2,097,152

    projKV_kernel<<<NB * (NS / 16), 256, 0, stream>>>(
        source_r, source_i, Wk_r, Wk_i, bk_r, bk_i, Wv_r, Wv_i, bv_r, Kh, VrT);

    attn_mfma_kernel<<<NB * (NT / 64), 256, 0, stream>>>(
        target_r, target_i, Wq_r, Wq_i, bq_r, bq_i, Kh, VrT, gamma,
        (float*)d_out);
}